// Round 2
// baseline (314.524 us; speedup 1.0000x reference)
//
#include <hip/hip_runtime.h>
#include <stdint.h>

// RandomSaltPepper: out = where(mask, color, imgs)
//   imgs: (64, 3, 512, 512) f32
//   mask  = uniform(k1, (B,1,H,W)) < 0.5     -> per-(b,h,w), shared over C
//   idx   = randint(k2, (B,1,H,W), 0, 2); color = idx==0 ? 1.0 : 0.0
//   k1,k2 = split(key(42))
//
// JAX randint internally does ANOTHER split: k2a_, k2b_ = split(k2);
// for span=2 the multiplier is 0, so idx = random_bits(k2b_) & 1.
// (jax/_src/random.py::_randint — higher_bits*0 + lower_bits%2)
//
// Exact JAX Threefry-2x32 replication, partitionable (default >= 0.4.30).
#define JAX_PARTITIONABLE 1

constexpr int B = 64, C = 3, H = 512, W = 512;
constexpr uint32_t HW   = (uint32_t)H * W;        // 262144
constexpr uint32_t NPIX = (uint32_t)B * HW;       // 16777216
constexpr uint32_t CHW  = (uint32_t)C * HW;

#define ROTL32(x, r) (((x) << (r)) | ((x) >> (32 - (r))))

__host__ __device__ __forceinline__ void tf2x32(uint32_t k0, uint32_t k1,
                                                uint32_t x0, uint32_t x1,
                                                uint32_t* o0, uint32_t* o1) {
  const uint32_t ks0 = k0, ks1 = k1, ks2 = k0 ^ k1 ^ 0x1BD11BDAu;
  x0 += ks0; x1 += ks1;
#define TF_R4(ra, rb, rc, rd)                      \
  x0 += x1; x1 = ROTL32(x1, ra); x1 ^= x0;         \
  x0 += x1; x1 = ROTL32(x1, rb); x1 ^= x0;         \
  x0 += x1; x1 = ROTL32(x1, rc); x1 ^= x0;         \
  x0 += x1; x1 = ROTL32(x1, rd); x1 ^= x0;
  TF_R4(13, 15, 26, 6);  x0 += ks1; x1 += ks2 + 1u;
  TF_R4(17, 29, 16, 24); x0 += ks2; x1 += ks0 + 2u;
  TF_R4(13, 15, 26, 6);  x0 += ks0; x1 += ks1 + 3u;
  TF_R4(17, 29, 16, 24); x0 += ks1; x1 += ks2 + 4u;
  TF_R4(13, 15, 26, 6);  x0 += ks2; x1 += ks0 + 5u;
#undef TF_R4
  *o0 = x0; *o1 = x1;
}

#if JAX_PARTITIONABLE
// 32-bit random word at flat index j: fold both halves of threefry(key, 0, j)
__device__ __forceinline__ uint32_t rand_word(uint32_t ka, uint32_t kb, uint32_t j) {
  uint32_t o0, o1;
  tf2x32(ka, kb, 0u, j, &o0, &o1);
  return o0 ^ o1;
}
#else
// Legacy: counts iota(N) split into halves; pairs (j, j+N/2);
// word(j) = j < N/2 ? out0(j, j+N/2) : out1(j-N/2, j)
__device__ __forceinline__ uint32_t rand_word(uint32_t ka, uint32_t kb, uint32_t j) {
  constexpr uint32_t HALF = NPIX / 2;
  uint32_t o0, o1;
  if (j < HALF) {
    tf2x32(ka, kb, j, j + HALF, &o0, &o1);
    return o0;
  } else {
    tf2x32(ka, kb, j - HALF, j, &o0, &o1);
    return o1;
  }
}
#endif

__global__ __launch_bounds__(256) void RandomSaltPepper_9380208574641_kernel(
    const float* __restrict__ in, float* __restrict__ out,
    uint32_t mka, uint32_t mkb, uint32_t cka, uint32_t ckb) {
  uint32_t j = blockIdx.x * 256u + threadIdx.x;
  if (j >= NPIX) return;

  // mask: uniform(mask_key) < 0.5  <=>  MSB of random word == 0
  const uint32_t mbits = rand_word(mka, mkb, j);
  const bool mask = (mbits & 0x80000000u) == 0u;
  // color: lower_bits(color_key) & 1 == 0 -> salt(1.0), else pepper(0.0)
  const uint32_t cbits = rand_word(cka, ckb, j);
  const float color = (cbits & 1u) ? 0.0f : 1.0f;

  const uint32_t b  = j >> 18;          // j / HW
  const uint32_t hw = j & (HW - 1u);    // j % HW
  const size_t base = (size_t)b * CHW + hw;

  const float v0 = in[base];
  const float v1 = in[base + HW];
  const float v2 = in[base + 2u * HW];
  out[base]           = mask ? color : v0;
  out[base + HW]      = mask ? color : v1;
  out[base + 2u * HW] = mask ? color : v2;
}

extern "C" void kernel_launch(void* const* d_in, const int* in_sizes, int n_in,
                              void* d_out, int out_size, void* d_ws, size_t ws_size,
                              hipStream_t stream) {
  const float* imgs = (const float*)d_in[0];
  float* out = (float*)d_out;

  // Host-side key derivation (deterministic, identical every call):
  //   k1, k2 = split(key(42)); color_key = split(k2)[1]
  const uint32_t pk0 = 0u, pk1 = 42u;
  uint32_t k1a, k1b, k2a, k2b, cka, ckb;
#if JAX_PARTITIONABLE
  // foldlike split: subkey i of split(key) = threefry(key, hi=0, lo=i)
  tf2x32(pk0, pk1, 0u, 0u, &k1a, &k1b);   // k1 (mask key)
  tf2x32(pk0, pk1, 0u, 1u, &k2a, &k2b);   // k2
  uint32_t t0, t1;
  tf2x32(k2a, k2b, 0u, 0u, &t0, &t1);     // split(k2)[0] (higher_bits, unused)
  tf2x32(k2a, k2b, 0u, 1u, &cka, &ckb);   // split(k2)[1] -> lower_bits key
  (void)t0; (void)t1;
#else
  // original split: counts [0,1,2,3] -> x0=[0,1], x1=[2,3];
  // keys = reshape(concat(o0,o1), (2,2)): k1=(o0(0,2),o0(1,3)), k2=(o1(0,2),o1(1,3))
  uint32_t a0, a1, b0, b1;
  tf2x32(pk0, pk1, 0u, 2u, &a0, &b0);
  tf2x32(pk0, pk1, 1u, 3u, &a1, &b1);
  k1a = a0; k1b = a1; k2a = b0; k2b = b1;
  // inner split(k2), same original scheme; lower_bits key = second row
  uint32_t c0, c1, d0, d1;
  tf2x32(k2a, k2b, 0u, 2u, &c0, &d0);
  tf2x32(k2a, k2b, 1u, 3u, &c1, &d1);
  cka = d0; ckb = d1;
#endif

  const int threads = 256;
  const int blocks = (int)(NPIX / (uint32_t)threads);  // 65536
  RandomSaltPepper_9380208574641_kernel<<<blocks, threads, 0, stream>>>(
      imgs, out, k1a, k1b, cka, ckb);
}